// Round 6
// baseline (1324.568 us; speedup 1.0000x reference)
//
#include <hip/hip_runtime.h>

typedef unsigned short ushort_t;
typedef __attribute__((ext_vector_type(8))) __bf16 bf16x8;
typedef __attribute__((ext_vector_type(4))) float f32x4;

__device__ __forceinline__ float bf2f(ushort_t u) {
    union { unsigned int i; float f; } v; v.i = ((unsigned int)u) << 16; return v.f;
}
__device__ __forceinline__ ushort_t f2bf(float f) {
    union { float f; unsigned int i; } v; v.f = f;
    unsigned int r = (v.i + 0x7FFFu + ((v.i >> 16) & 1u)) >> 16;
    return (ushort_t)r;
}
__device__ __forceinline__ float gelu_exact(float v) {
    return 0.5f * v * (1.f + erff(v * 0.70710678118654752f));
}
// dtype-agnostic scalar load: isf32 ? f32[i] : bf16[i]
__device__ __forceinline__ float ld1(const void* p, size_t i, int isf32) {
    return isf32 ? ((const float*)p)[i] : bf2f(((const ushort_t*)p)[i]);
}
// dtype-agnostic 8-elem load -> 8 bf16 (16B) in dst
__device__ __forceinline__ void stage8(const void* p, size_t idx, int isf32, ushort_t* dst) {
    if (isf32) {
        const float* f = (const float*)p + idx;
        float4 u = *(const float4*)f;
        float4 v = *(const float4*)(f + 4);
        dst[0] = f2bf(u.x); dst[1] = f2bf(u.y); dst[2] = f2bf(u.z); dst[3] = f2bf(u.w);
        dst[4] = f2bf(v.x); dst[5] = f2bf(v.y); dst[6] = f2bf(v.z); dst[7] = f2bf(v.w);
    } else {
        *(uint4*)dst = *(const uint4*)((const ushort_t*)p + idx);
    }
}

// ---------------------------------------------------------------------------
// dtype detect on x: low halfword of each 32b word. flag: 1=f32, 0=bf16.
// ---------------------------------------------------------------------------
__global__ void detect_kernel(const unsigned int* __restrict__ x, int* __restrict__ flag) {
    if (threadIdx.x == 0 && blockIdx.x == 0) {
        int sane = 0;
        for (int i = 0; i < 256; i++) {
            unsigned int e = (x[i] >> 7) & 0xFFu;
            if (e == 0u || (e >= 100u && e <= 140u)) sane++;
        }
        *flag = (sane >= 200) ? 0 : 1;
    }
}

// ---------------------------------------------------------------------------
// prep_consts
// ---------------------------------------------------------------------------
__global__ void prep_consts_kernel(const void* __restrict__ temps,
                                   const void* __restrict__ biases,
                                   const void* __restrict__ gating,
                                   float* __restrict__ consts,
                                   const int* __restrict__ dflag) {
    if (threadIdx.x == 0 && blockIdx.x == 0) {
        int isf32 = *dflag;
        float g = tanhf(ld1(gating, 0, isf32));
        for (int s = 0; s < 4; s++) {
            float t  = ld1(temps, s, isf32);
            float sp = (t > 20.f) ? t : log1pf(expf(t));
            float scale = 0.125f * (1.f + sp);   // HD^-0.5 = 1/8
            float mul = (s == 3) ? g : 1.f;
            consts[s]     = scale * mul;
            consts[4 + s] = ld1(biases, s, isf32) * mul;
        }
    }
}

// ---------------------------------------------------------------------------
// AdaLN modulation
// ---------------------------------------------------------------------------
__global__ void __launch_bounds__(256) adaln_kernel(
    const void* __restrict__ cond, const void* __restrict__ w,
    const void* __restrict__ bias, float* __restrict__ mod,
    const int* __restrict__ dflag) {
    __shared__ float cs[1024];
    int isf32 = *dflag;
    int b = blockIdx.y, tid = threadIdx.x;
    for (int i = tid; i < 1024; i += 256) {
        float c = ld1(cond, b * 1024 + i, isf32);
        cs[i] = c / (1.f + expf(-c));
    }
    __syncthreads();
    int n = blockIdx.x * 256 + tid;
    float acc = 0.f;
    if (isf32) {
        const float* wr = (const float*)w + (size_t)n * 1024;
        for (int d = 0; d < 1024; d += 8) {
            float4 a = *(const float4*)(wr + d);
            float4 bb = *(const float4*)(wr + d + 4);
            acc += cs[d+0]*a.x + cs[d+1]*a.y + cs[d+2]*a.z + cs[d+3]*a.w
                 + cs[d+4]*bb.x + cs[d+5]*bb.y + cs[d+6]*bb.z + cs[d+7]*bb.w;
        }
    } else {
        const ushort_t* wr = (const ushort_t*)w + (size_t)n * 1024;
        for (int d = 0; d < 1024; d += 8) {
            uint4 raw = *(const uint4*)(wr + d);
            const ushort_t* u = (const ushort_t*)&raw;
            acc += cs[d+0]*bf2f(u[0]) + cs[d+1]*bf2f(u[1]) + cs[d+2]*bf2f(u[2]) + cs[d+3]*bf2f(u[3])
                 + cs[d+4]*bf2f(u[4]) + cs[d+5]*bf2f(u[5]) + cs[d+6]*bf2f(u[6]) + cs[d+7]*bf2f(u[7]);
        }
    }
    mod[(size_t)b * 6144 + n] = acc + ld1(bias, n, isf32);
}

// ---------------------------------------------------------------------------
// LayerNorm + AdaLN modulation
// ---------------------------------------------------------------------------
template <int SRC>
__global__ void __launch_bounds__(256) ln_mod_kernel(
    const void* __restrict__ xin, const float* __restrict__ mod,
    const void* __restrict__ lnw, const void* __restrict__ lnb,
    int shift_off, int scale_off, ushort_t* __restrict__ out,
    const int* __restrict__ dflag) {
    int isf32 = *dflag;
    int row = blockIdx.x, tid = threadIdx.x;
    int b = row >> 9;
    float v[4];
    #pragma unroll
    for (int i = 0; i < 4; i++) {
        size_t idx = (size_t)row * 1024 + tid + 256 * i;
        v[i] = (SRC == 1) ? ((const float*)xin)[idx] : ld1(xin, idx, isf32);
    }
    float s = v[0] + v[1] + v[2] + v[3];
    float ss = v[0]*v[0] + v[1]*v[1] + v[2]*v[2] + v[3]*v[3];
    #pragma unroll
    for (int off = 1; off < 64; off <<= 1) {
        s  += __shfl_xor(s,  off, 64);
        ss += __shfl_xor(ss, off, 64);
    }
    __shared__ float red[8];
    int w = tid >> 6;
    if ((tid & 63) == 0) { red[w] = s; red[4 + w] = ss; }
    __syncthreads();
    s  = red[0] + red[1] + red[2] + red[3];
    ss = red[4] + red[5] + red[6] + red[7];
    float mean = s * (1.f / 1024.f);
    float var  = ss * (1.f / 1024.f) - mean * mean;
    float inv  = rsqrtf(var + 1e-5f);
    const float* mb = mod + (size_t)b * 6144;
    #pragma unroll
    for (int i = 0; i < 4; i++) {
        int d = tid + 256 * i;
        float xn = (v[i] - mean) * inv;
        float y  = xn * ld1(lnw, d, isf32) + ld1(lnb, d, isf32);
        out[(size_t)row * 1024 + d] = f2bf(y * (1.f + mb[scale_off + d]) + mb[shift_off + d]);
    }
}

// ---------------------------------------------------------------------------
// FAST GEMM: C(M,N) = A(M,K) @ W(wrow0+n, :)^T + bias[wrow0+n].
// BM in {64,128}, BN = 128 fixed, BK = 64. 4 waves, wave tile BM/2 x 64,
// MF x 4 fragment grid, padded LDS [BM][72] (~2 lanes/bank frag reads).
// In-flight f32->bf16 conversion during staging (stage8).
// EPI: 0 = f32 row-major, 1 = bf16 row-major, 2 = bf16 + exact GELU,
//      3 = bf16 KV head-major scatter out[((b*16+h)*1792 + p0 + t)*64 + d]
//      4 = bf16 Q head-major scatter  out[(((b*16+h)*4 + p0)*512 + t)*64 + d]
//      5 = bf16 V TRANSPOSED scatter  out[((b*16+h)*64 + d)*1792 + p0 + t]
// ---------------------------------------------------------------------------
template <int BM, int EPI>
__global__ void __launch_bounds__(256) gemm_fast_kernel(
    const void* __restrict__ A, int lda,
    const void* __restrict__ W, int wrow0,
    const void* __restrict__ bias,
    void* __restrict__ Cout, int ldc, int K, int p0, int p1,
    int a_ext, const int* __restrict__ dflag) {
    constexpr int BN = 128;
    constexpr int MF = BM / 32;       // m-frags per wave
    constexpr int NF = 4;             // n-frags per wave
    constexpr int CA = BM * 8 / 256;  // A staging chunks per thread
    constexpr int CB = BN * 8 / 256;  // B staging chunks per thread
    __shared__ ushort_t As[BM][72];
    __shared__ ushort_t Bs[BN][72];
    int isf32 = *dflag;
    int fa = a_ext ? isf32 : 0;
    int m0 = blockIdx.y * BM, n0 = blockIdx.x * BN;
    int tid = threadIdx.x;
    int w = tid >> 6, ln = tid & 63;
    int msub = (w & 1) * (BM / 2), nsub = (w >> 1) * 64;
    int m = ln & 15, quad = ln >> 4;
    f32x4 acc[MF][NF];
    #pragma unroll
    for (int i = 0; i < MF; i++)
        #pragma unroll
        for (int j = 0; j < NF; j++) acc[i][j] = (f32x4){0.f, 0.f, 0.f, 0.f};

    for (int k0 = 0; k0 < K; k0 += 64) {
        __syncthreads();
        #pragma unroll
        for (int i = 0; i < CA; i++) {
            int c = i * 256 + tid;
            int row = c >> 3, col = (c & 7) * 8;
            ushort_t t8[8];
            stage8(A, (size_t)(m0 + row) * lda + k0 + col, fa, t8);
            *(uint4*)&As[row][col] = *(uint4*)t8;
        }
        #pragma unroll
        for (int i = 0; i < CB; i++) {
            int c = i * 256 + tid;
            int row = c >> 3, col = (c & 7) * 8;
            ushort_t t8[8];
            stage8(W, (size_t)(wrow0 + n0 + row) * K + k0 + col, isf32, t8);
            *(uint4*)&Bs[row][col] = *(uint4*)t8;
        }
        __syncthreads();
        #pragma unroll
        for (int ko = 0; ko < 2; ko++) {
            bf16x8 af[MF], bfr[NF];
            #pragma unroll
            for (int mi = 0; mi < MF; mi++)
                af[mi] = *(const bf16x8*)&As[msub + mi * 16 + m][ko * 32 + quad * 8];
            #pragma unroll
            for (int ni = 0; ni < NF; ni++)
                bfr[ni] = *(const bf16x8*)&Bs[nsub + ni * 16 + m][ko * 32 + quad * 8];
            #pragma unroll
            for (int mi = 0; mi < MF; mi++)
                #pragma unroll
                for (int ni = 0; ni < NF; ni++)
                    acc[mi][ni] = __builtin_amdgcn_mfma_f32_16x16x32_bf16(af[mi], bfr[ni], acc[mi][ni], 0, 0, 0);
        }
    }
    // epilogue
    int col0 = n0 + nsub + m;
    float bv[NF];
    #pragma unroll
    for (int ni = 0; ni < NF; ni++) bv[ni] = ld1(bias, wrow0 + col0 + ni * 16, isf32);
    #pragma unroll
    for (int mi = 0; mi < MF; mi++) {
        #pragma unroll
        for (int ni = 0; ni < NF; ni++) {
            int col = col0 + ni * 16;
            #pragma unroll
            for (int e = 0; e < 4; e++) {
                int rowg = m0 + msub + mi * 16 + quad * 4 + e;
                float v = acc[mi][ni][e] + bv[ni];
                if (EPI == 2) v = gelu_exact(v);
                if (EPI == 0) {
                    ((float*)Cout)[(size_t)rowg * ldc + col] = v;
                } else if (EPI == 1 || EPI == 2) {
                    ((ushort_t*)Cout)[(size_t)rowg * ldc + col] = f2bf(v);
                } else if (EPI == 3) {
                    int b = rowg >> p1, t = rowg & ((1 << p1) - 1);
                    ((ushort_t*)Cout)[(((size_t)(b * 16 + (col >> 6))) * 1792 + p0 + t) * 64 + (col & 63)] = f2bf(v);
                } else if (EPI == 5) {
                    int b = rowg >> p1, t = rowg & ((1 << p1) - 1);
                    ((ushort_t*)Cout)[(((size_t)(b * 16 + (col >> 6))) * 64 + (col & 63)) * 1792 + p0 + t] = f2bf(v);
                } else {  // EPI == 4
                    int b = rowg >> 9, t = rowg & 511;
                    ((ushort_t*)Cout)[((((size_t)(b * 16 + (col >> 6))) * 4 + p0) * 512 + t) * 64 + (col & 63)] = f2bf(v);
                }
            }
        }
    }
}

// ---------------------------------------------------------------------------
// In-place Q: RMSNorm(qn_w) all sets + RoPE (set 0 only)
// ---------------------------------------------------------------------------
__global__ void __launch_bounds__(256) qrope_ip_kernel(
    ushort_t* __restrict__ qbuf, const void* __restrict__ qnw,
    const int* __restrict__ dflag) {
    int isf32 = *dflag;
    int w = threadIdx.x >> 6, ln = threadIdx.x & 63;
    int flat = blockIdx.x * 4 + w;
    int t = flat & 511, s = (flat >> 9) & 3;
    ushort_t* p = qbuf + (size_t)flat * 64;
    float x = bf2f(p[ln]);
    float ssum = x * x;
    #pragma unroll
    for (int off = 1; off < 64; off <<= 1) ssum += __shfl_xor(ssum, off, 64);
    float y = x * rsqrtf(ssum * (1.f / 64.f) + 1e-6f) * ld1(qnw, ln, isf32);
    if (s == 0) {
        float ang = (float)t * expf(-(float)(ln & 31) * (9.210340371976184f / 32.f));
        float cs, sn;
        sincosf(ang, &sn, &cs);
        float other = __shfl_xor(y, 32, 64);
        y = y * cs + ((ln < 32) ? -other : other) * sn;
    }
    p[ln] = f2bf(y);
}

// ---------------------------------------------------------------------------
// In-place K: RMSNorm(kn_w) + RoPE; t = j & 511
// ---------------------------------------------------------------------------
__global__ void __launch_bounds__(256) krope_ip_kernel(
    ushort_t* __restrict__ kbuf, const void* __restrict__ knw,
    const int* __restrict__ dflag) {
    int isf32 = *dflag;
    int w = threadIdx.x >> 6, ln = threadIdx.x & 63;
    int flat = blockIdx.x * 4 + w;
    int j = flat % 1792;
    int t = j & 511;
    ushort_t* p = kbuf + (size_t)flat * 64;
    float x = bf2f(p[ln]);
    float ssum = x * x;
    #pragma unroll
    for (int off = 1; off < 64; off <<= 1) ssum += __shfl_xor(ssum, off, 64);
    float y = x * rsqrtf(ssum * (1.f / 64.f) + 1e-6f) * ld1(knw, ln, isf32);
    float ang = (float)t * expf(-(float)(ln & 31) * (9.210340371976184f / 32.f));
    float cs, sn;
    sincosf(ang, &sn, &cs);
    float other = __shfl_xor(y, 32, 64);
    y = y * cs + ((ln < 32) ? -other : other) * sn;
    p[ln] = f2bf(y);
}

// ---------------------------------------------------------------------------
// MFMA flash attention, joint softmax over 4 sources. (unchanged from R5)
// ---------------------------------------------------------------------------
__global__ void __launch_bounds__(256) attn_mfma_kernel(
    const ushort_t* __restrict__ qbuf, const ushort_t* __restrict__ kbuf,
    const ushort_t* __restrict__ vbufT, const float* __restrict__ consts,
    ushort_t* __restrict__ attn_out) {
    __shared__ ushort_t ks[32][72];
    __shared__ ushort_t vsT[64][40];
    __shared__ ushort_t ps[4][16][40];
    int bh = blockIdx.y;
    int b = bh >> 4, h = bh & 15;
    int tid = threadIdx.x, w = tid >> 6, ln = tid & 63;
    int r0 = blockIdx.x * 64 + w * 16;
    int m = ln & 15, quad = ln >> 4;

    const ushort_t* qb = qbuf + (size_t)bh * 4 * 512 * 64;
    bf16x8 qf00 = *(const bf16x8*)(qb + ((size_t)(0 * 512 + r0 + m)) * 64 + quad * 8);
    bf16x8 qf01 = *(const bf16x8*)(qb + ((size_t)(0 * 512 + r0 + m)) * 64 + 32 + quad * 8);
    bf16x8 qf10 = *(const bf16x8*)(qb + ((size_t)(1 * 512 + r0 + m)) * 64 + quad * 8);
    bf16x8 qf11 = *(const bf16x8*)(qb + ((size_t)(1 * 512 + r0 + m)) * 64 + 32 + quad * 8);
    bf16x8 qf20 = *(const bf16x8*)(qb + ((size_t)(2 * 512 + r0 + m)) * 64 + quad * 8);
    bf16x8 qf21 = *(const bf16x8*)(qb + ((size_t)(2 * 512 + r0 + m)) * 64 + 32 + quad * 8);
    bf16x8 qf30 = *(const bf16x8*)(qb + ((size_t)(3 * 512 + r0 + m)) * 64 + quad * 8);
    bf16x8 qf31 = *(const bf16x8*)(qb + ((size_t)(3 * 512 + r0 + m)) * 64 + 32 + quad * 8);

    float m_i[4], l_i[4];
    f32x4 acc[4];
    #pragma unroll
    for (int e = 0; e < 4; e++) { m_i[e] = -1e30f; l_i[e] = 0.f; }
    #pragma unroll
    for (int d = 0; d < 4; d++) acc[d] = (f32x4){0.f, 0.f, 0.f, 0.f};

    const ushort_t* kb  = kbuf  + (size_t)bh * 1792 * 64;
    const ushort_t* vbT = vbufT + (size_t)bh * 64 * 1792;
    int skey = tid >> 3, sd = (tid & 7) * 8;
    int vrow = tid >> 2, vcol = (tid & 3) * 8;

    uint4 kreg = *(const uint4*)(kb + (size_t)skey * 64 + sd);
    uint4 vreg = *(const uint4*)(vbT + (size_t)vrow * 1792 + vcol);
    int tcnt = 0;

    #pragma unroll
    for (int s = 0; s < 4; s++) {
        const float a_s = consts[s];
        const float b_s = consts[4 + s];
        const bf16x8 qA0 = (s == 0) ? qf00 : (s == 1) ? qf10 : (s == 2) ? qf20 : qf30;
        const bf16x8 qA1 = (s == 0) ? qf01 : (s == 1) ? qf11 : (s == 2) ? qf21 : qf31;
        const int NT = (s == 3) ? 8 : 16;
        for (int ti = 0; ti < NT; ti++) {
            __syncthreads();
            *(uint4*)&ks[skey][sd] = kreg;
            *(uint4*)&vsT[vrow][vcol] = vreg;
            if (tcnt < 55) {
                int nx = (tcnt + 1) * 32;
                kreg = *(const uint4*)(kb + (size_t)(nx + skey) * 64 + sd);
                vreg = *(const uint4*)(vbT + (size_t)vrow * 1792 + nx + vcol);
            }
            __syncthreads();
            f32x4 zero = {0.f, 0.f, 0.f, 0.f};
            bf16x8 b00 = *(const bf16x8*)&ks[m][quad * 8];
            bf16x8 b01 = *(const bf16x8*)&ks[m][32 + quad * 8];
            bf16x8 b10 = *(const bf16x8*)&ks[16 + m][quad * 8];
            bf16x8 b11 = *(const bf16x8*)&ks[16 + m][32 + quad * 8];
            f32x4 sc0 = __builtin_amdgcn_mfma_f32_16x16x32_bf16(qA0, b00, zero, 0, 0, 0);
            sc0 = __builtin_amdgcn_mfma_f32_16x16x32_bf16(qA1, b01, sc0, 0, 0, 0);
            f32x4 sc1 = __builtin_amdgcn_mfma_f32_16x16x32_bf16(qA0, b10, zero, 0, 0, 0);
            sc1 = __builtin_amdgcn_mfma_f32_16x16x32_bf16(qA1, b11, sc1, 0, 0, 0);
            #pragma unroll
            for (int e = 0; e < 4; e++) {
                float s0 = sc0[e] * a_s + b_s;
                float s1 = sc1[e] * a_s + b_s;
                float mxe = fmaxf(s0, s1);
                #pragma unroll
                for (int off = 1; off < 16; off <<= 1) mxe = fmaxf(mxe, __shfl_xor(mxe, off, 64));
                float mnew = fmaxf(m_i[e], mxe);
                float p0 = __expf(s0 - mnew), p1 = __expf(s1 - mnew);
                float rsum = p0 + p1;
                #pragma unroll
                for (int off = 1; off < 16; off <<= 1) rsum += __shfl_xor(rsum, off, 64);
                float alpha = __expf(m_i[e] - mnew);
                m_i[e] = mnew;
                l_i[e] = l_i[e] * alpha + rsum;
                acc[0][e] *= alpha; acc[1][e] *= alpha;
                acc[2][e] *= alpha; acc[3][e] *= alpha;
                int row = quad * 4 + e;
                ps[w][row][m]      = f2bf(p0);
                ps[w][row][m + 16] = f2bf(p1);
            }
            bf16x8 pA = *(const bf16x8*)&ps[w][m][quad * 8];
            #pragma unroll
            for (int dsub = 0; dsub < 4; dsub++) {
                bf16x8 vB = *(const bf16x8*)&vsT[dsub * 16 + m][quad * 8];
                acc[dsub] = __builtin_amdgcn_mfma_f32_16x16x32_bf16(pA, vB, acc[dsub], 0, 0, 0);
            }
            tcnt++;
        }
    }
    #pragma unroll
    for (int e = 0; e < 4; e++) {
        int t = r0 + quad * 4 + e;
        float invl = 1.f / l_i[e];
        #pragma unroll
        for (int dsub = 0; dsub < 4; dsub++) {
            int d = dsub * 16 + m;
            attn_out[(((size_t)(b * 512 + t)) * 16 + h) * 64 + d] = f2bf(acc[dsub][e] * invl);
        }
    }
}

// ---------------------------------------------------------------------------
// residual gates
// ---------------------------------------------------------------------------
__global__ void resgate_kernel(const void* __restrict__ x, const float* __restrict__ proj,
                               const float* __restrict__ mod, float* __restrict__ x1,
                               const int* __restrict__ dflag) {
    int isf32 = *dflag;
    int i = blockIdx.x * 256 + threadIdx.x;
    int b = i >> 19, n = i & 1023;
    x1[i] = ld1(x, i, isf32) + mod[(size_t)b * 6144 + 2048 + n] * proj[i];
}
__global__ void final_kernel(const float* __restrict__ x1, const float* __restrict__ ffn,
                             const float* __restrict__ mod, void* __restrict__ out,
                             const int* __restrict__ dflag) {
    int isf32 = *dflag;
    int i = blockIdx.x * 256 + threadIdx.x;
    int b = i >> 19, n = i & 1023;
    float val = x1[i] + mod[(size_t)b * 6144 + 5120 + n] * ffn[i];
    if (isf32) ((float*)out)[i] = val;
    else       ((ushort_t*)out)[i] = f2bf(val);
}

// ---------------------------------------------------------------------------
// workspace layout (bytes) — total ~56.1 MB, lifetime-checked aliases.
// ---------------------------------------------------------------------------
static constexpr size_t OFF_CONSTS   = 0;
static constexpr size_t OFF_FLAG     = 64;
static constexpr size_t OFF_MOD      = 512;
static constexpr size_t OFF_XNORM    = OFF_MOD    + 98304;
static constexpr size_t OFF_QAH      = OFF_XNORM  + 4194304;
static constexpr size_t OFF_KBUF     = OFF_XNORM  + 8388608;
static constexpr size_t OFF_VBUF     = OFF_KBUF   + 14680064;   // vbufT[bh][d][key]
static constexpr size_t OFF_QBUF     = OFF_VBUF   + 14680064;
static constexpr size_t OFF_ATTNOUT  = OFF_QBUF   + 16777216;
static constexpr size_t OFF_X1       = OFF_XNORM;
static constexpr size_t OFF_ATTNPROJ = OFF_QBUF;
static constexpr size_t OFF_FFNOUT   = OFF_QBUF   + 8388608;
static constexpr size_t OFF_HMID     = OFF_KBUF;
static constexpr size_t OFF_HIN      = OFF_ATTNOUT;

extern "C" void kernel_launch(void* const* d_in, const int* in_sizes, int n_in,
                              void* d_out, int out_size, void* d_ws, size_t ws_size,
                              hipStream_t stream) {
    (void)in_sizes; (void)n_in; (void)out_size; (void)ws_size;
    const void* x        = d_in[0];
    const void* bev      = d_in[1];
    const void* vl       = d_in[2];
    const void* reas     = d_in[3];
    const void* cond     = d_in[4];
    const void* ln_pre_w = d_in[5];
    const void* ln_pre_b = d_in[6];
    const void* adaln_w  = d_in[7];
    const void* adaln_b  = d_in[8];
    const void* q_proj_w = d_in[9];
    const void* q_proj_b = d_in[10];
    const void* qa_w     = d_in[11];
    const void* qa_b     = d_in[12];
    const void* qa_out_w = d_in[13];
    const void* qa_out_b = d_in[14];
    const void* k_w      = d_in[15];
    const void* k_b      = d_in[16];
    const void* v_w      = d_in[17];
    const void* v_b      = d_in[18];
    const void* o_w      = d_in[19];
    const void* o_b      = d_in[20];
    const void* qn_w     = d_in[21];
    const void* kn_w     = d_in[22];
    const void* gating   = d_in[23];
    const void* temps    = d_in[24];
    const void* sbias    = d_in[25];
    const void* ffn_ln_w = d_in[26];
    const void* ffn_ln_b = d_in[27];
    const void* ffn_w1   = d_in[28];
    const void* ffn_b1   = d_in[29];
    const void* ffn_w2   = d_in[30];
    const void* ffn_b2   = d_in[31];

    char* ws = (char*)d_ws;
    float*    consts   = (float*)(ws + OFF_CONSTS);
    int*      dflag    = (int*)(ws + OFF_FLAG);
    float*    mod      = (float*)(ws + OFF_MOD);
    ushort_t* xnorm    = (ushort_t*)(ws + OFF_XNORM);
    ushort_t* qah      = (ushort_t*)(ws + OFF_QAH);
    ushort_t* kbuf     = (ushort_t*)(ws + OFF_KBUF);
    ushort_t* vbufT    = (ushort_t*)(ws + OFF_VBUF);
    ushort_t* qbuf     = (ushort_t*)(ws + OFF_QBUF);
    ushort_t* attnout  = (ushort_t*)(ws + OFF_ATTNOUT);
    float*    x1       = (float*)(ws + OFF_X1);
    float*    attnproj = (float*)(ws + OFF_ATTNPROJ);
    float*    ffnout   = (float*)(ws + OFF_FFNOUT);
    ushort_t* hmid     = (ushort_t*)(ws + OFF_HMID);
    ushort_t* hin      = (ushort_t*)(ws + OFF_HIN);

    // 0. dtype detect
    detect_kernel<<<1, 64, 0, stream>>>((const unsigned int*)x, dflag);
    // 1. consts + AdaLN mod
    prep_consts_kernel<<<1, 64, 0, stream>>>(temps, sbias, gating, consts, dflag);
    adaln_kernel<<<dim3(24, 4), 256, 0, stream>>>(cond, adaln_w, adaln_b, mod, dflag);
    // 2. pre-LN with modulation
    ln_mod_kernel<0><<<2048, 256, 0, stream>>>(x, mod, ln_pre_w, ln_pre_b, 0, 1024, xnorm, dflag);
    // 3. q_self -> qbuf set 0   (grid: x = N/128, y = M/64)
    gemm_fast_kernel<64, 4><<<dim3(8, 32), 256, 0, stream>>>(xnorm, 1024, q_proj_w, 0, q_proj_b, qbuf, 0, 1024, 0, 9, 0, dflag);
    // 4. K/V per source (V stored transposed)
    {
        const void* srcs[4] = {xnorm, bev, vl, reas};
        const int koffs[4] = {0, 512, 1024, 1536};
        const int p1s[4]   = {9, 9, 9, 8};
        for (int i = 0; i < 4; i++) {
            int aext = (i == 0) ? 0 : 1;
            int gy = (i == 3) ? 16 : 32;   // M/64
            gemm_fast_kernel<64, 3><<<dim3(8, gy), 256, 0, stream>>>(
                srcs[i], 1024, k_w, i * 1024, k_b, kbuf, 0, 1024, koffs[i], p1s[i], aext, dflag);
            gemm_fast_kernel<64, 5><<<dim3(8, gy), 256, 0, stream>>>(
                srcs[i], 1024, v_w, i * 1024, v_b, vbufT, 0, 1024, koffs[i], p1s[i], aext, dflag);
        }
    }
    // 5. adapter queries -> qbuf sets 1..3
    gemm_fast_kernel<64, 1><<<dim3(6, 32), 256, 0, stream>>>(xnorm, 1024, qa_w, 0, qa_b, qah, 768, 1024, 0, 0, 0, dflag);
    for (int i = 0; i < 3; i++)
        gemm_fast_kernel<64, 4><<<dim3(8, 32), 256, 0, stream>>>(qah + i * 256, 768, qa_out_w, 0, qa_out_b,
                                                                 qbuf, 0, 256, 1 + i, 9, 0, dflag);
    // 6. in-place QK-norm + RoPE
    qrope_ip_kernel<<<32768, 256, 0, stream>>>(qbuf, qn_w, dflag);
    krope_ip_kernel<<<28672, 256, 0, stream>>>(kbuf, kn_w, dflag);
    // 7. MFMA joint-softmax flash attention
    attn_mfma_kernel<<<dim3(8, 64), 256, 0, stream>>>(qbuf, kbuf, vbufT, consts, attnout);
    // 8. output projection + gated residual
    gemm_fast_kernel<64, 0><<<dim3(8, 32), 256, 0, stream>>>(attnout, 1024, o_w, 0, o_b, attnproj, 1024, 1024, 0, 0, 0, dflag);
    resgate_kernel<<<8192, 256, 0, stream>>>(x, attnproj, mod, x1, dflag);
    // 9. FFN with exact GELU
    ln_mod_kernel<1><<<2048, 256, 0, stream>>>(x1, mod, ffn_ln_w, ffn_ln_b, 3072, 4096, hin, dflag);
    gemm_fast_kernel<128, 2><<<dim3(32, 16), 256, 0, stream>>>(hin, 1024, ffn_w1, 0, ffn_b1, hmid, 4096, 1024, 0, 0, 0, dflag);
    gemm_fast_kernel<64, 0><<<dim3(8, 32), 256, 0, stream>>>(hmid, 4096, ffn_w2, 0, ffn_b2, ffnout, 1024, 4096, 0, 0, 0, dflag);
    final_kernel<<<8192, 256, 0, stream>>>(x1, ffnout, mod, d_out, dflag);
}

// Round 9
// 826.185 us; speedup vs baseline: 1.6032x; 1.6032x over previous
//
#include <hip/hip_runtime.h>

typedef unsigned short ushort_t;
typedef __attribute__((ext_vector_type(8))) __bf16 bf16x8;
typedef __attribute__((ext_vector_type(4))) float f32x4;

__device__ __forceinline__ float bf2f(ushort_t u) {
    union { unsigned int i; float f; } v; v.i = ((unsigned int)u) << 16; return v.f;
}
__device__ __forceinline__ ushort_t f2bf(float f) {
    union { float f; unsigned int i; } v; v.f = f;
    unsigned int r = (v.i + 0x7FFFu + ((v.i >> 16) & 1u)) >> 16;
    return (ushort_t)r;
}
__device__ __forceinline__ float gelu_exact(float v) {
    return 0.5f * v * (1.f + erff(v * 0.70710678118654752f));
}
__device__ __forceinline__ float ld1(const void* p, size_t i, int isf32) {
    return isf32 ? ((const float*)p)[i] : bf2f(((const ushort_t*)p)[i]);
}
__device__ __forceinline__ void stage8(const void* p, size_t idx, int isf32, ushort_t* dst) {
    if (isf32) {
        const float* f = (const float*)p + idx;
        float4 u = *(const float4*)f;
        float4 v = *(const float4*)(f + 4);
        dst[0] = f2bf(u.x); dst[1] = f2bf(u.y); dst[2] = f2bf(u.z); dst[3] = f2bf(u.w);
        dst[4] = f2bf(v.x); dst[5] = f2bf(v.y); dst[6] = f2bf(v.z); dst[7] = f2bf(v.w);
    } else {
        *(uint4*)dst = *(const uint4*)((const ushort_t*)p + idx);
    }
}

__global__ void detect_kernel(const unsigned int* __restrict__ x, int* __restrict__ flag) {
    if (threadIdx.x == 0 && blockIdx.x == 0) {
        int sane = 0;
        for (int i = 0; i < 256; i++) {
            unsigned int e = (x[i] >> 7) & 0xFFu;
            if (e == 0u || (e >= 100u && e <= 140u)) sane++;
        }
        *flag = (sane >= 200) ? 0 : 1;
    }
}

static constexpr size_t CV_ADALN = 0;          // 6144x1024
static constexpr size_t CV_QPROJ = 6291456;    // 1024x1024
static constexpr size_t CV_QA    = 7340032;    // 3x256x1024
static constexpr size_t CV_QAOUT = 8126464;    // 1024x256
static constexpr size_t CV_KW    = 8388608;    // 4x1024x1024
static constexpr size_t CV_VW    = 12582912;   // 4x1024x1024
static constexpr size_t CV_OW    = 16777216;   // 1024x1024
static constexpr size_t CV_FFN1  = 17825792;   // 4096x1024
static constexpr size_t CV_FFN2  = 22020096;   // 1024x4096
static constexpr size_t CV_TOTAL = 26214400;   // elements (x2 bytes = 50 MB)

__global__ void __launch_bounds__(256) convert_weights_kernel(
    const void* s0, const void* s1, const void* s2, const void* s3,
    const void* s4, const void* s5, const void* s6, const void* s7,
    const void* s8, ushort_t* __restrict__ dst, const int* __restrict__ dflag) {
    int isf32 = *dflag;
    size_t i8 = ((size_t)blockIdx.x * 256 + threadIdx.x) * 8;
    if (i8 >= CV_TOTAL) return;
    const void* src; size_t base;
    if      (i8 < CV_QPROJ) { src = s0; base = CV_ADALN; }
    else if (i8 < CV_QA)    { src = s1; base = CV_QPROJ; }
    else if (i8 < CV_QAOUT) { src = s2; base = CV_QA; }
    else if (i8 < CV_KW)    { src = s3; base = CV_QAOUT; }
    else if (i8 < CV_VW)    { src = s4; base = CV_KW; }
    else if (i8 < CV_OW)    { src = s5; base = CV_VW; }
    else if (i8 < CV_FFN1)  { src = s6; base = CV_OW; }
    else if (i8 < CV_FFN2)  { src = s7; base = CV_FFN1; }
    else                    { src = s8; base = CV_FFN2; }
    ushort_t t8[8];
    stage8(src, i8 - base, isf32, t8);
    *(uint4*)(dst + i8) = *(uint4*)t8;
}

__global__ void prep_consts_kernel(const void* __restrict__ temps,
                                   const void* __restrict__ biases,
                                   const void* __restrict__ gating,
                                   float* __restrict__ consts,
                                   const int* __restrict__ dflag) {
    if (threadIdx.x == 0 && blockIdx.x == 0) {
        int isf32 = *dflag;
        float g = tanhf(ld1(gating, 0, isf32));
        for (int s = 0; s < 4; s++) {
            float t  = ld1(temps, s, isf32);
            float sp = (t > 20.f) ? t : log1pf(expf(t));
            float scale = 0.125f * (1.f + sp);
            float mul = (s == 3) ? g : 1.f;
            consts[s]     = scale * mul;
            consts[4 + s] = ld1(biases, s, isf32) * mul;
        }
    }
}

__global__ void __launch_bounds__(256) adaln_kernel(
    const void* __restrict__ cond, const void* __restrict__ w,
    const void* __restrict__ bias, float* __restrict__ mod,
    int wmode, const int* __restrict__ dflag) {
    __shared__ float cs[1024];
    int isf32 = *dflag;
    int wf = (wmode == 2) ? 0 : isf32;
    int b = blockIdx.y, tid = threadIdx.x;
    for (int i = tid; i < 1024; i += 256) {
        float c = ld1(cond, b * 1024 + i, isf32);
        cs[i] = c / (1.f + expf(-c));
    }
    __syncthreads();
    int n = blockIdx.x * 256 + tid;
    float acc = 0.f;
    if (wf) {
        const float* wr = (const float*)w + (size_t)n * 1024;
        for (int d = 0; d < 1024; d += 8) {
            float4 a = *(const float4*)(wr + d);
            float4 bb = *(const float4*)(wr + d + 4);
            acc += cs[d+0]*a.x + cs[d+1]*a.y + cs[d+2]*a.z + cs[d+3]*a.w
                 + cs[d+4]*bb.x + cs[d+5]*bb.y + cs[d+6]*bb.z + cs[d+7]*bb.w;
        }
    } else {
        const ushort_t* wr = (const ushort_t*)w + (size_t)n * 1024;
        for (int d = 0; d < 1024; d += 8) {
            uint4 raw = *(const uint4*)(wr + d);
            const ushort_t* u = (const ushort_t*)&raw;
            acc += cs[d+0]*bf2f(u[0]) + cs[d+1]*bf2f(u[1]) + cs[d+2]*bf2f(u[2]) + cs[d+3]*bf2f(u[3])
                 + cs[d+4]*bf2f(u[4]) + cs[d+5]*bf2f(u[5]) + cs[d+6]*bf2f(u[6]) + cs[d+7]*bf2f(u[7]);
        }
    }
    mod[(size_t)b * 6144 + n] = acc + ld1(bias, n, isf32);
}

template <int SRC>
__global__ void __launch_bounds__(256) ln_mod_kernel(
    const void* __restrict__ xin, const float* __restrict__ mod,
    const void* __restrict__ lnw, const void* __restrict__ lnb,
    int shift_off, int scale_off, ushort_t* __restrict__ out,
    const int* __restrict__ dflag) {
    int isf32 = *dflag;
    int row = blockIdx.x, tid = threadIdx.x;
    int b = row >> 9;
    float v[4];
    #pragma unroll
    for (int i = 0; i < 4; i++) {
        size_t idx = (size_t)row * 1024 + tid + 256 * i;
        v[i] = (SRC == 1) ? ((const float*)xin)[idx] : ld1(xin, idx, isf32);
    }
    float s = v[0] + v[1] + v[2] + v[3];
    float ss = v[0]*v[0] + v[1]*v[1] + v[2]*v[2] + v[3]*v[3];
    #pragma unroll
    for (int off = 1; off < 64; off <<= 1) {
        s  += __shfl_xor(s,  off, 64);
        ss += __shfl_xor(ss, off, 64);
    }
    __shared__ float red[8];
    int w = tid >> 6;
    if ((tid & 63) == 0) { red[w] = s; red[4 + w] = ss; }
    __syncthreads();
    s  = red[0] + red[1] + red[2] + red[3];
    ss = red[4] + red[5] + red[6] + red[7];
    float mean = s * (1.f / 1024.f);
    float var  = ss * (1.f / 1024.f) - mean * mean;
    float inv  = rsqrtf(var + 1e-5f);
    const float* mb = mod + (size_t)b * 6144;
    #pragma unroll
    for (int i = 0; i < 4; i++) {
        int d = tid + 256 * i;
        float xn = (v[i] - mean) * inv;
        float y  = xn * ld1(lnw, d, isf32) + ld1(lnb, d, isf32);
        out[(size_t)row * 1024 + d] = f2bf(y * (1.f + mb[scale_off + d]) + mb[shift_off + d]);
    }
}

template <int EPI>
__global__ void __launch_bounds__(256) gemm_bt_kernel(
    const void* __restrict__ A, int lda,
    const void* __restrict__ W, int wrow0,
    const void* __restrict__ bias,
    void* __restrict__ Cout, int ldc, int K, int p0, int p1,
    int a_ext, int wmode, const int* __restrict__ dflag) {
    __shared__ ushort_t As[64][40];
    __shared__ ushort_t Bs[64][40];
    int isf32 = *dflag;
    int fa = a_ext ? isf32 : 0;
    int fw = (wmode == 2) ? 0 : isf32;
    int m0 = blockIdx.y * 64, n0 = blockIdx.x * 64;
    int tid = threadIdx.x;
    int r = tid >> 2, c = (tid & 3) * 8;
    int w = tid >> 6, ln = tid & 63;
    int msub = (w & 1) * 32, nsub = (w >> 1) * 32;
    int fr = ln & 15, q = ln >> 4;
    f32x4 acc00 = {0.f,0.f,0.f,0.f}, acc01 = {0.f,0.f,0.f,0.f};
    f32x4 acc10 = {0.f,0.f,0.f,0.f}, acc11 = {0.f,0.f,0.f,0.f};
    for (int k0 = 0; k0 < K; k0 += 32) {
        __syncthreads();
        {
            ushort_t t8[8];
            stage8(A, (size_t)(m0 + r) * lda + c + k0, fa, t8);
            *(uint4*)&As[r][c] = *(uint4*)t8;
        }
        {
            ushort_t t8[8];
            stage8(W, (size_t)(wrow0 + n0 + r) * K + c + k0, fw, t8);
            *(uint4*)&Bs[r][c] = *(uint4*)t8;
        }
        __syncthreads();
        bf16x8 a0 = *(const bf16x8*)&As[msub + fr][q * 8];
        bf16x8 a1 = *(const bf16x8*)&As[msub + 16 + fr][q * 8];
        bf16x8 b0 = *(const bf16x8*)&Bs[nsub + fr][q * 8];
        bf16x8 b1 = *(const bf16x8*)&Bs[nsub + 16 + fr][q * 8];
        acc00 = __builtin_amdgcn_mfma_f32_16x16x32_bf16(a0, b0, acc00, 0, 0, 0);
        acc01 = __builtin_amdgcn_mfma_f32_16x16x32_bf16(a0, b1, acc01, 0, 0, 0);
        acc10 = __builtin_amdgcn_mfma_f32_16x16x32_bf16(a1, b0, acc10, 0, 0, 0);
        acc11 = __builtin_amdgcn_mfma_f32_16x16x32_bf16(a1, b1, acc11, 0, 0, 0);
    }
    int col0 = n0 + nsub + fr;
    float bv0 = ld1(bias, wrow0 + col0, isf32);
    float bv1 = ld1(bias, wrow0 + col0 + 16, isf32);
    #pragma unroll
    for (int mi = 0; mi < 2; mi++) {
        #pragma unroll
        for (int ni = 0; ni < 2; ni++) {
            f32x4 a = (mi == 0) ? (ni == 0 ? acc00 : acc01) : (ni == 0 ? acc10 : acc11);
            int col = col0 + ni * 16;
            float bb = (ni == 0) ? bv0 : bv1;
            #pragma unroll
            for (int e = 0; e < 4; e++) {
                int rowg = m0 + msub + mi * 16 + q * 4 + e;
                float v = a[e] + bb;
                if (EPI == 2) v = gelu_exact(v);
                if (EPI == 0) {
                    ((float*)Cout)[(size_t)rowg * ldc + col] = v;
                } else if (EPI == 1 || EPI == 2) {
                    ((ushort_t*)Cout)[(size_t)rowg * ldc + col] = f2bf(v);
                } else if (EPI == 3) {
                    int b = rowg >> p1, t = rowg & ((1 << p1) - 1);
                    ((ushort_t*)Cout)[(((size_t)(b * 16 + (col >> 6))) * 1792 + p0 + t) * 64 + (col & 63)] = f2bf(v);
                } else if (EPI == 5) {
                    int b = rowg >> p1, t = rowg & ((1 << p1) - 1);
                    ((ushort_t*)Cout)[(((size_t)(b * 16 + (col >> 6))) * 64 + (col & 63)) * 1792 + p0 + t] = f2bf(v);
                } else {  // EPI == 4
                    int b = rowg >> 9, t = rowg & 511;
                    ((ushort_t*)Cout)[((((size_t)(b * 16 + (col >> 6))) * 4 + p0) * 512 + t) * 64 + (col & 63)] = f2bf(v);
                }
            }
        }
    }
}

__global__ void __launch_bounds__(256) qrope_ip_kernel(
    ushort_t* __restrict__ qbuf, const void* __restrict__ qnw,
    const int* __restrict__ dflag) {
    int isf32 = *dflag;
    int w = threadIdx.x >> 6, ln = threadIdx.x & 63;
    int flat = blockIdx.x * 4 + w;
    int t = flat & 511, s = (flat >> 9) & 3;
    ushort_t* p = qbuf + (size_t)flat * 64;
    float x = bf2f(p[ln]);
    float ssum = x * x;
    #pragma unroll
    for (int off = 1; off < 64; off <<= 1) ssum += __shfl_xor(ssum, off, 64);
    float y = x * rsqrtf(ssum * (1.f / 64.f) + 1e-6f) * ld1(qnw, ln, isf32);
    if (s == 0) {
        float ang = (float)t * expf(-(float)(ln & 31) * (9.210340371976184f / 32.f));
        float cs, sn;
        sincosf(ang, &sn, &cs);
        float other = __shfl_xor(y, 32, 64);
        y = y * cs + ((ln < 32) ? -other : other) * sn;
    }
    p[ln] = f2bf(y);
}

__global__ void __launch_bounds__(256) krope_ip_kernel(
    ushort_t* __restrict__ kbuf, const void* __restrict__ knw,
    const int* __restrict__ dflag) {
    int isf32 = *dflag;
    int w = threadIdx.x >> 6, ln = threadIdx.x & 63;
    int flat = blockIdx.x * 4 + w;
    int j = flat % 1792;
    int t = j & 511;
    ushort_t* p = kbuf + (size_t)flat * 64;
    float x = bf2f(p[ln]);
    float ssum = x * x;
    #pragma unroll
    for (int off = 1; off < 64; off <<= 1) ssum += __shfl_xor(ssum, off, 64);
    float y = x * rsqrtf(ssum * (1.f / 64.f) + 1e-6f) * ld1(knw, ln, isf32);
    float ang = (float)t * expf(-(float)(ln & 31) * (9.210340371976184f / 32.f));
    float cs, sn;
    sincosf(ang, &sn, &cs);
    float other = __shfl_xor(y, 32, 64);
    y = y * cs + ((ln < 32) ? -other : other) * sn;
    p[ln] = f2bf(y);
}

__global__ void __launch_bounds__(256) attn_mfma_kernel(
    const ushort_t* __restrict__ qbuf, const ushort_t* __restrict__ kbuf,
    const ushort_t* __restrict__ vbufT, const float* __restrict__ consts,
    ushort_t* __restrict__ attn_out) {
    __shared__ ushort_t ks[32][72];
    __shared__ ushort_t vsT[64][40];
    __shared__ ushort_t ps[4][16][40];
    int bh = blockIdx.y;
    int b = bh >> 4, h = bh & 15;
    int tid = threadIdx.x, w = tid >> 6, ln = tid & 63;
    int r0 = blockIdx.x * 64 + w * 16;
    int m = ln & 15, quad = ln >> 4;

    const ushort_t* qb = qbuf + (size_t)bh * 4 * 512 * 64;
    bf16x8 qf00 = *(const bf16x8*)(qb + ((size_t)(0 * 512 + r0 + m)) * 64 + quad * 8);
    bf16x8 qf01 = *(const bf16x8*)(qb + ((size_t)(0 * 512 + r0 + m)) * 64 + 32 + quad * 8);
    bf16x8 qf10 = *(const bf16x8*)(qb + ((size_t)(1 * 512 + r0 + m)) * 64 + quad * 8);
    bf16x8 qf11 = *(const bf16x8*)(qb + ((size_t)(1 * 512 + r0 + m)) * 64 + 32 + quad * 8);
    bf16x8 qf20 = *(const bf16x8*)(qb + ((size_t)(2 * 512 + r0 + m)) * 64 + quad * 8);
    bf16x8 qf21 = *(const bf16x8*)(qb + ((size_t)(2 * 512 + r0 + m)) * 64 + 32 + quad * 8);
    bf16x8 qf30 = *(const bf16x8*)(qb + ((size_t)(3 * 512 + r0 + m)) * 64 + quad * 8);
    bf16x8 qf31 = *(const bf16x8*)(qb + ((size_t)(3 * 512 + r0 + m)) * 64 + 32 + quad * 8);

    float m_i[4], l_i[4];
    f32x4 acc[4];
    #pragma unroll
    for (int e = 0; e < 4; e++) { m_i[e] = -1e30f; l_i[e] = 0.f; }
    #pragma unroll
    for (int d = 0; d < 4; d++) acc[d] = (f32x4){0.f, 0.f, 0.f, 0.f};

    const ushort_t* kb  = kbuf  + (size_t)bh * 1792 * 64;
    const ushort_t* vbT = vbufT + (size_t)bh * 64 * 1792;
    int skey = tid >> 3, sd = (tid & 7) * 8;
    int vrow = tid >> 2, vcol = (tid & 3) * 8;

    uint4 kreg = *(const uint4*)(kb + (size_t)skey * 64 + sd);
    uint4 vreg = *(const uint4*)(vbT + (size_t)vrow * 1792 + vcol);
    int tcnt = 0;

    #pragma unroll
    for (int s = 0; s < 4; s++) {
        const float a_s = consts[s];
        const float b_s = consts[4 + s];
        const bf16x8 qA0 = (s == 0) ? qf00 : (s == 1) ? qf10 : (s == 2) ? qf20 : qf30;
        const bf16x8 qA1 = (s == 0) ? qf01 : (s == 1) ? qf11 : (s == 2) ? qf21 : qf31;
        const int NT = (s == 3) ? 8 : 16;
        for (int ti = 0; ti < NT; ti++) {
            __syncthreads();
            *(uint4*)&ks[skey][sd] = kreg;
            *(uint4*)&vsT[vrow][vcol] = vreg;
            if (tcnt < 55) {
                int nx = (tcnt + 1) * 32;
                kreg = *(const uint4*)(kb + (size_t)(nx + skey) * 64 + sd);
                vreg = *(const uint4*)(vbT + (size_t)vrow * 1792 + nx + vcol);
            }
            __syncthreads();
            f32x4 zero = {0.f, 0.f, 0.f, 0.f};
            bf16x8 b00 = *(const bf16x8*)&ks[m][quad * 8];
            bf16x8 b01 = *(const bf16x8*)&ks[m][32 + quad * 8];
            bf16x8 b10 = *(const bf16x8*)&ks[16 + m][quad * 8];
            bf16x8 b11 = *(const bf16x8*)&ks[16 + m][32 + quad * 8];
            f32x4 sc0 = __builtin_amdgcn_mfma_f32_16x16x32_bf16(qA0, b00, zero, 0, 0, 0);
            sc0 = __builtin_amdgcn_mfma_f32_16x16x32_bf16(qA1, b01, sc0, 0, 0, 0);
            f32x4 sc1 = __builtin_amdgcn_mfma_f32_16x16x32_bf16(qA0, b10, zero, 0, 0, 0);
            sc1 = __builtin_amdgcn_mfma_f32_16x16x32_bf16(qA1, b11, sc1, 0, 0, 0);
            #pragma unroll
            for (int e = 0; e < 4; e++) {
                float s0 = sc0[e] * a_s + b_s;
                float s1 = sc1[e] * a_s + b_s;
                float mxe = fmaxf(s0, s1);
                #pragma unroll
                for (int off = 1; off < 16; off <<= 1) mxe = fmaxf(mxe, __shfl_xor(mxe, off, 64));
                float mnew = fmaxf(m_i[e], mxe);
                float p0 = __expf(s0 - mnew), p1 = __expf(s1 - mnew);
                float rsum = p0 + p1;
                #pragma unroll
                for (int off = 1; off < 16; off <<= 1) rsum += __shfl_xor(rsum, off, 64);
                float alpha = __expf(m_i[e] - mnew);
                m_i[e] = mnew;
                l_i[e] = l_i[e] * alpha + rsum;
                acc[0][e] *= alpha; acc[1][e] *= alpha;
                acc[2][e] *= alpha; acc[3][e] *= alpha;
                int row = quad * 4 + e;
                ps[w][row][m]      = f2bf(p0);
                ps[w][row][m + 16] = f2bf(p1);
            }
            bf16x8 pA = *(const bf16x8*)&ps[w][m][quad * 8];
            #pragma unroll
            for (int dsub = 0; dsub < 4; dsub++) {
                bf16x8 vB = *(const bf16x8*)&vsT[dsub * 16 + m][quad * 8];
                acc[dsub] = __builtin_amdgcn_mfma_f32_16x16x32_bf16(pA, vB, acc[dsub], 0, 0, 0);
            }
            tcnt++;
        }
    }
    #pragma unroll
    for (int e = 0; e < 4; e++) {
        int t = r0 + quad * 4 + e;
        float invl = 1.f / l_i[e];
        #pragma unroll
        for (int dsub = 0; dsub < 4; dsub++) {
            int d = dsub * 16 + m;
            attn_out[(((size_t)(b * 512 + t)) * 16 + h) * 64 + d] = f2bf(acc[dsub][e] * invl);
        }
    }
}

__global__ void resgate_kernel(const void* __restrict__ x, const float* __restrict__ proj,
                               const float* __restrict__ mod, float* __restrict__ x1,
                               const int* __restrict__ dflag) {
    int isf32 = *dflag;
    int i = blockIdx.x * 256 + threadIdx.x;
    int b = i >> 19, n = i & 1023;
    x1[i] = ld1(x, i, isf32) + mod[(size_t)b * 6144 + 2048 + n] * proj[i];
}
__global__ void final_kernel(const float* __restrict__ x1, const float* __restrict__ ffn,
                             const float* __restrict__ mod, void* __restrict__ out,
                             const int* __restrict__ dflag) {
    int isf32 = *dflag;
    int i = blockIdx.x * 256 + threadIdx.x;
    int b = i >> 19, n = i & 1023;
    float val = x1[i] + mod[(size_t)b * 6144 + 5120 + n] * ffn[i];
    if (isf32) ((float*)out)[i] = val;
    else       ((ushort_t*)out)[i] = f2bf(val);
}

static constexpr size_t OFF_CONSTS   = 0;
static constexpr size_t OFF_FLAG     = 64;
static constexpr size_t OFF_MOD      = 512;
static constexpr size_t OFF_XNORM    = OFF_MOD    + 98304;
static constexpr size_t OFF_QAH      = OFF_XNORM  + 4194304;
static constexpr size_t OFF_KBUF     = OFF_XNORM  + 8388608;
static constexpr size_t OFF_VBUF     = OFF_KBUF   + 14680064;   // vbufT[bh][d][key]
static constexpr size_t OFF_QBUF     = OFF_VBUF   + 14680064;
static constexpr size_t OFF_ATTNOUT  = OFF_QBUF   + 16777216;
static constexpr size_t OFF_X1       = OFF_XNORM;
static constexpr size_t OFF_ATTNPROJ = OFF_QBUF;
static constexpr size_t OFF_FFNOUT   = OFF_QBUF   + 8388608;
static constexpr size_t OFF_HMID     = OFF_KBUF;
static constexpr size_t OFF_HIN      = OFF_ATTNOUT;
static constexpr size_t OFF_WCACHE   = OFF_ATTNOUT + 4194304;   // bf16 weight cache
static constexpr size_t WS_NEED      = OFF_WCACHE + CV_TOTAL * 2;

extern "C" void kernel_launch(void* const* d_in, const int* in_sizes, int n_in,
                              void* d_out, int out_size, void* d_ws, size_t ws_size,
                              hipStream_t stream) {
    (void)in_sizes; (void)n_in; (void)out_size;
    const void* x        = d_in[0];
    const void* bev      = d_in[1];
    const void* vl       = d_in[2];
    const void* reas     = d_in[3];
    const void* cond     = d_in[4];
    const void* ln_pre_w = d_in[5];
    const void* ln_pre_b = d_in[6];
    const void* adaln_w  = d_in[7];
    const void* adaln_b  = d_in[8];
    const void* q_proj_w = d_in[9];
    const void* q_proj_b = d_in[10];
    const void* qa_w     = d_in[11];
    const void* qa_b     = d_in[12];
    const void* qa_out_w = d_in[13];
    const void* qa_out_b = d_in[14];
    const void* k_w      = d_in[15];
    const void* k_b      = d_in[16];
    const void* v_w      = d_in[17];
    const void* v_b      = d_in[18];
    const void* o_w      = d_in[19];
    const void* o_b      = d_in[20];
    const void* qn_w     = d_in[21];
    const void* kn_w     = d_in[22];
    const void* gating   = d_in[23];
    const void* temps    = d_in[24];
    const void* sbias    = d_in[25];
    const void* ffn_ln_w = d_in[26];
    const void* ffn_ln_b = d_in[27];
    const void* ffn_w1   = d_in[28];
    const void* ffn_b1   = d_in[29];
    const void* ffn_w2   = d_in[30];
    const void* ffn_b2   = d_in[31];

    char* ws = (char*)d_ws;
    float*    consts   = (float*)(ws + OFF_CONSTS);
    int*      dflag    = (int*)(ws + OFF_FLAG);
    float*    mod      = (float*)(ws + OFF_MOD);
    ushort_t* xnorm    = (ushort_t*)(ws + OFF_XNORM);
    ushort_t* qah      = (ushort_t*)(ws + OFF_QAH);
    ushort_t* kbuf     = (ushort_t*)(ws + OFF_KBUF);
    ushort_t* vbufT    = (ushort_t*)(ws + OFF_VBUF);
    ushort_t* qbuf     = (ushort_t*)(ws + OFF_QBUF);
    ushort_t* attnout  = (ushort_t*)(ws + OFF_ATTNOUT);
    float*    x1       = (float*)(ws + OFF_X1);
    float*    attnproj = (float*)(ws + OFF_ATTNPROJ);
    float*    ffnout   = (float*)(ws + OFF_FFNOUT);
    ushort_t* hmid     = (ushort_t*)(ws + OFF_HMID);
    ushort_t* hin      = (ushort_t*)(ws + OFF_HIN);
    ushort_t* wc       = (ushort_t*)(ws + OFF_WCACHE);

    const bool use_cache = (ws_size >= WS_NEED);
    const int  wm = use_cache ? 2 : 0;
    const void* W_adaln = use_cache ? (const void*)(wc + CV_ADALN) : adaln_w;
    const void* W_qproj = use_cache ? (const void*)(wc + CV_QPROJ) : q_proj_w;
    const void* W_qa    = use_cache ? (const void*)(wc + CV_QA)    : qa_w;
    const void* W_qaout = use_cache ? (const void*)(wc + CV_QAOUT) : qa_out_w;
    const void* W_k     = use_cache ? (const void*)(wc + CV_KW)    : k_w;
    const void* W_v     = use_cache ? (const void*)(wc + CV_VW)    : v_w;
    const void* W_o     = use_cache ? (const void*)(wc + CV_OW)    : o_w;
    const void* W_ffn1  = use_cache ? (const void*)(wc + CV_FFN1)  : ffn_w1;
    const void* W_ffn2  = use_cache ? (const void*)(wc + CV_FFN2)  : ffn_w2;

    detect_kernel<<<1, 64, 0, stream>>>((const unsigned int*)x, dflag);
    if (use_cache)
        convert_weights_kernel<<<12800, 256, 0, stream>>>(
            adaln_w, q_proj_w, qa_w, qa_out_w, k_w, v_w, o_w, ffn_w1, ffn_w2, wc, dflag);
    prep_consts_kernel<<<1, 64, 0, stream>>>(temps, sbias, gating, consts, dflag);
    adaln_kernel<<<dim3(24, 4), 256, 0, stream>>>(cond, W_adaln, adaln_b, mod, wm, dflag);
    ln_mod_kernel<0><<<2048, 256, 0, stream>>>(x, mod, ln_pre_w, ln_pre_b, 0, 1024, xnorm, dflag);
    gemm_bt_kernel<4><<<dim3(16, 32), 256, 0, stream>>>(xnorm, 1024, W_qproj, 0, q_proj_b, qbuf, 0, 1024, 0, 9, 0, wm, dflag);
    {
        const void* srcs[4] = {xnorm, bev, vl, reas};
        const int koffs[4] = {0, 512, 1024, 1536};
        const int p1s[4]   = {9, 9, 9, 8};
        for (int i = 0; i < 4; i++) {
            int aext = (i == 0) ? 0 : 1;
            int gy = (i == 3) ? 16 : 32;
            gemm_bt_kernel<3><<<dim3(16, gy), 256, 0, stream>>>(
                srcs[i], 1024, W_k, i * 1024, k_b, kbuf, 0, 1024, koffs[i], p1s[i], aext, wm, dflag);
            gemm_bt_kernel<5><<<dim3(16, gy), 256, 0, stream>>>(
                srcs[i], 1024, W_v, i * 1024, v_b, vbufT, 0, 1024, koffs[i], p1s[i], aext, wm, dflag);
        }
    }
    gemm_bt_kernel<1><<<dim3(12, 32), 256, 0, stream>>>(xnorm, 1024, W_qa, 0, qa_b, qah, 768, 1024, 0, 0, 0, wm, dflag);
    for (int i = 0; i < 3; i++)
        gemm_bt_kernel<4><<<dim3(16, 32), 256, 0, stream>>>(qah + i * 256, 768, W_qaout, 0, qa_out_b,
                                                            qbuf, 0, 256, 1 + i, 9, 0, wm, dflag);
    qrope_ip_kernel<<<32768, 256, 0, stream>>>(qbuf, qn_w, dflag);
    krope_ip_kernel<<<28672, 256, 0, stream>>>(kbuf, kn_w, dflag);
    attn_mfma_kernel<<<dim3(8, 64), 256, 0, stream>>>(qbuf, kbuf, vbufT, consts, attnout);
    gemm_bt_kernel<0><<<dim3(16, 32), 256, 0, stream>>>(attnout, 1024, W_o, 0, o_b, attnproj, 1024, 1024, 0, 0, 0, wm, dflag);
    resgate_kernel<<<8192, 256, 0, stream>>>(x, attnproj, mod, x1, dflag);
    ln_mod_kernel<1><<<2048, 256, 0, stream>>>(x1, mod, ffn_ln_w, ffn_ln_b, 3072, 4096, hin, dflag);
    gemm_bt_kernel<2><<<dim3(64, 32), 256, 0, stream>>>(hin, 1024, W_ffn1, 0, ffn_b1, hmid, 4096, 1024, 0, 0, 0, wm, dflag);
    gemm_bt_kernel<0><<<dim3(16, 32), 256, 0, stream>>>(hmid, 4096, W_ffn2, 0, ffn_b2, ffnout, 1024, 4096, 0, 0, 0, wm, dflag);
    final_kernel<<<8192, 256, 0, stream>>>(x1, ffnout, mod, d_out, dflag);
}

// Round 10
// 779.242 us; speedup vs baseline: 1.6998x; 1.0602x over previous
//
#include <hip/hip_runtime.h>

typedef unsigned short ushort_t;
typedef __attribute__((ext_vector_type(8))) __bf16 bf16x8;
typedef __attribute__((ext_vector_type(4))) float f32x4;

__device__ __forceinline__ float bf2f(ushort_t u) {
    union { unsigned int i; float f; } v; v.i = ((unsigned int)u) << 16; return v.f;
}
__device__ __forceinline__ ushort_t f2bf(float f) {
    union { float f; unsigned int i; } v; v.f = f;
    unsigned int r = (v.i + 0x7FFFu + ((v.i >> 16) & 1u)) >> 16;
    return (ushort_t)r;
}
__device__ __forceinline__ float gelu_exact(float v) {
    return 0.5f * v * (1.f + erff(v * 0.70710678118654752f));
}
__device__ __forceinline__ float ld1(const void* p, size_t i, int isf32) {
    return isf32 ? ((const float*)p)[i] : bf2f(((const ushort_t*)p)[i]);
}
__device__ __forceinline__ void stage8(const void* p, size_t idx, int isf32, ushort_t* dst) {
    if (isf32) {
        const float* f = (const float*)p + idx;
        float4 u = *(const float4*)f;
        float4 v = *(const float4*)(f + 4);
        dst[0] = f2bf(u.x); dst[1] = f2bf(u.y); dst[2] = f2bf(u.z); dst[3] = f2bf(u.w);
        dst[4] = f2bf(v.x); dst[5] = f2bf(v.y); dst[6] = f2bf(v.z); dst[7] = f2bf(v.w);
    } else {
        *(uint4*)dst = *(const uint4*)((const ushort_t*)p + idx);
    }
}

__global__ void detect_kernel(const unsigned int* __restrict__ x, int* __restrict__ flag) {
    if (threadIdx.x == 0 && blockIdx.x == 0) {
        int sane = 0;
        for (int i = 0; i < 256; i++) {
            unsigned int e = (x[i] >> 7) & 0xFFu;
            if (e == 0u || (e >= 100u && e <= 140u)) sane++;
        }
        *flag = (sane >= 200) ? 0 : 1;
    }
}

static constexpr size_t CV_ADALN = 0;          // 6144x1024
static constexpr size_t CV_QPROJ = 6291456;    // 1024x1024
static constexpr size_t CV_QA    = 7340032;    // 3x256x1024
static constexpr size_t CV_QAOUT = 8126464;    // 1024x256
static constexpr size_t CV_KW    = 8388608;    // 4x1024x1024
static constexpr size_t CV_VW    = 12582912;   // 4x1024x1024
static constexpr size_t CV_OW    = 16777216;   // 1024x1024
static constexpr size_t CV_FFN1  = 17825792;   // 4096x1024
static constexpr size_t CV_FFN2  = 22020096;   // 1024x4096
static constexpr size_t CV_TOTAL = 26214400;   // elements (x2 bytes = 50 MB)

__global__ void __launch_bounds__(256) convert_weights_kernel(
    const void* s0, const void* s1, const void* s2, const void* s3,
    const void* s4, const void* s5, const void* s6, const void* s7,
    const void* s8, ushort_t* __restrict__ dst, const int* __restrict__ dflag) {
    int isf32 = *dflag;
    size_t i8 = ((size_t)blockIdx.x * 256 + threadIdx.x) * 8;
    if (i8 >= CV_TOTAL) return;
    const void* src; size_t base;
    if      (i8 < CV_QPROJ) { src = s0; base = CV_ADALN; }
    else if (i8 < CV_QA)    { src = s1; base = CV_QPROJ; }
    else if (i8 < CV_QAOUT) { src = s2; base = CV_QA; }
    else if (i8 < CV_KW)    { src = s3; base = CV_QAOUT; }
    else if (i8 < CV_VW)    { src = s4; base = CV_KW; }
    else if (i8 < CV_OW)    { src = s5; base = CV_VW; }
    else if (i8 < CV_FFN1)  { src = s6; base = CV_OW; }
    else if (i8 < CV_FFN2)  { src = s7; base = CV_FFN1; }
    else                    { src = s8; base = CV_FFN2; }
    ushort_t t8[8];
    stage8(src, i8 - base, isf32, t8);
    *(uint4*)(dst + i8) = *(uint4*)t8;
}

__global__ void prep_consts_kernel(const void* __restrict__ temps,
                                   const void* __restrict__ biases,
                                   const void* __restrict__ gating,
                                   float* __restrict__ consts,
                                   const int* __restrict__ dflag) {
    if (threadIdx.x == 0 && blockIdx.x == 0) {
        int isf32 = *dflag;
        float g = tanhf(ld1(gating, 0, isf32));
        for (int s = 0; s < 4; s++) {
            float t  = ld1(temps, s, isf32);
            float sp = (t > 20.f) ? t : log1pf(expf(t));
            float scale = 0.125f * (1.f + sp);
            float mul = (s == 3) ? g : 1.f;
            consts[s]     = scale * mul;
            consts[4 + s] = ld1(biases, s, isf32) * mul;
        }
    }
}

__global__ void __launch_bounds__(256) adaln_kernel(
    const void* __restrict__ cond, const void* __restrict__ w,
    const void* __restrict__ bias, float* __restrict__ mod,
    int wmode, const int* __restrict__ dflag) {
    __shared__ float cs[1024];
    int isf32 = *dflag;
    int wf = (wmode == 2) ? 0 : isf32;
    int b = blockIdx.y, tid = threadIdx.x;
    for (int i = tid; i < 1024; i += 256) {
        float c = ld1(cond, b * 1024 + i, isf32);
        cs[i] = c / (1.f + expf(-c));
    }
    __syncthreads();
    int n = blockIdx.x * 256 + tid;
    float acc = 0.f;
    if (wf) {
        const float* wr = (const float*)w + (size_t)n * 1024;
        for (int d = 0; d < 1024; d += 8) {
            float4 a = *(const float4*)(wr + d);
            float4 bb = *(const float4*)(wr + d + 4);
            acc += cs[d+0]*a.x + cs[d+1]*a.y + cs[d+2]*a.z + cs[d+3]*a.w
                 + cs[d+4]*bb.x + cs[d+5]*bb.y + cs[d+6]*bb.z + cs[d+7]*bb.w;
        }
    } else {
        const ushort_t* wr = (const ushort_t*)w + (size_t)n * 1024;
        for (int d = 0; d < 1024; d += 8) {
            uint4 raw = *(const uint4*)(wr + d);
            const ushort_t* u = (const ushort_t*)&raw;
            acc += cs[d+0]*bf2f(u[0]) + cs[d+1]*bf2f(u[1]) + cs[d+2]*bf2f(u[2]) + cs[d+3]*bf2f(u[3])
                 + cs[d+4]*bf2f(u[4]) + cs[d+5]*bf2f(u[5]) + cs[d+6]*bf2f(u[6]) + cs[d+7]*bf2f(u[7]);
        }
    }
    mod[(size_t)b * 6144 + n] = acc + ld1(bias, n, isf32);
}

template <int SRC>
__global__ void __launch_bounds__(256) ln_mod_kernel(
    const void* __restrict__ xin, const float* __restrict__ mod,
    const void* __restrict__ lnw, const void* __restrict__ lnb,
    int shift_off, int scale_off, ushort_t* __restrict__ out,
    const int* __restrict__ dflag) {
    int isf32 = *dflag;
    int row = blockIdx.x, tid = threadIdx.x;
    int b = row >> 9;
    float v[4];
    #pragma unroll
    for (int i = 0; i < 4; i++) {
        size_t idx = (size_t)row * 1024 + tid + 256 * i;
        v[i] = (SRC == 1) ? ((const float*)xin)[idx] : ld1(xin, idx, isf32);
    }
    float s = v[0] + v[1] + v[2] + v[3];
    float ss = v[0]*v[0] + v[1]*v[1] + v[2]*v[2] + v[3]*v[3];
    #pragma unroll
    for (int off = 1; off < 64; off <<= 1) {
        s  += __shfl_xor(s,  off, 64);
        ss += __shfl_xor(ss, off, 64);
    }
    __shared__ float red[8];
    int w = tid >> 6;
    if ((tid & 63) == 0) { red[w] = s; red[4 + w] = ss; }
    __syncthreads();
    s  = red[0] + red[1] + red[2] + red[3];
    ss = red[4] + red[5] + red[6] + red[7];
    float mean = s * (1.f / 1024.f);
    float var  = ss * (1.f / 1024.f) - mean * mean;
    float inv  = rsqrtf(var + 1e-5f);
    const float* mb = mod + (size_t)b * 6144;
    #pragma unroll
    for (int i = 0; i < 4; i++) {
        int d = tid + 256 * i;
        float xn = (v[i] - mean) * inv;
        float y  = xn * ld1(lnw, d, isf32) + ld1(lnb, d, isf32);
        out[(size_t)row * 1024 + d] = f2bf(y * (1.f + mb[scale_off + d]) + mb[shift_off + d]);
    }
}

// ---------------------------------------------------------------------------
// GEMM: blockIdx.x = M-blocks (fast-moving), blockIdx.y = N-blocks so that
// concurrently-dispatched blocks share the same 64 W rows (L2-resident).
// ---------------------------------------------------------------------------
template <int EPI>
__global__ void __launch_bounds__(256) gemm_bt_kernel(
    const void* __restrict__ A, int lda,
    const void* __restrict__ W, int wrow0,
    const void* __restrict__ bias,
    void* __restrict__ Cout, int ldc, int K, int p0, int p1,
    int a_ext, int wmode, const int* __restrict__ dflag) {
    __shared__ ushort_t As[64][40];
    __shared__ ushort_t Bs[64][40];
    int isf32 = *dflag;
    int fa = a_ext ? isf32 : 0;
    int fw = (wmode == 2) ? 0 : isf32;
    int m0 = blockIdx.x * 64, n0 = blockIdx.y * 64;
    int tid = threadIdx.x;
    int r = tid >> 2, c = (tid & 3) * 8;
    int w = tid >> 6, ln = tid & 63;
    int msub = (w & 1) * 32, nsub = (w >> 1) * 32;
    int fr = ln & 15, q = ln >> 4;
    f32x4 acc00 = {0.f,0.f,0.f,0.f}, acc01 = {0.f,0.f,0.f,0.f};
    f32x4 acc10 = {0.f,0.f,0.f,0.f}, acc11 = {0.f,0.f,0.f,0.f};
    for (int k0 = 0; k0 < K; k0 += 32) {
        __syncthreads();
        {
            ushort_t t8[8];
            stage8(A, (size_t)(m0 + r) * lda + c + k0, fa, t8);
            *(uint4*)&As[r][c] = *(uint4*)t8;
        }
        {
            ushort_t t8[8];
            stage8(W, (size_t)(wrow0 + n0 + r) * K + c + k0, fw, t8);
            *(uint4*)&Bs[r][c] = *(uint4*)t8;
        }
        __syncthreads();
        bf16x8 a0 = *(const bf16x8*)&As[msub + fr][q * 8];
        bf16x8 a1 = *(const bf16x8*)&As[msub + 16 + fr][q * 8];
        bf16x8 b0 = *(const bf16x8*)&Bs[nsub + fr][q * 8];
        bf16x8 b1 = *(const bf16x8*)&Bs[nsub + 16 + fr][q * 8];
        acc00 = __builtin_amdgcn_mfma_f32_16x16x32_bf16(a0, b0, acc00, 0, 0, 0);
        acc01 = __builtin_amdgcn_mfma_f32_16x16x32_bf16(a0, b1, acc01, 0, 0, 0);
        acc10 = __builtin_amdgcn_mfma_f32_16x16x32_bf16(a1, b0, acc10, 0, 0, 0);
        acc11 = __builtin_amdgcn_mfma_f32_16x16x32_bf16(a1, b1, acc11, 0, 0, 0);
    }
    int col0 = n0 + nsub + fr;
    float bv0 = ld1(bias, wrow0 + col0, isf32);
    float bv1 = ld1(bias, wrow0 + col0 + 16, isf32);
    #pragma unroll
    for (int mi = 0; mi < 2; mi++) {
        #pragma unroll
        for (int ni = 0; ni < 2; ni++) {
            f32x4 a = (mi == 0) ? (ni == 0 ? acc00 : acc01) : (ni == 0 ? acc10 : acc11);
            int col = col0 + ni * 16;
            float bb = (ni == 0) ? bv0 : bv1;
            #pragma unroll
            for (int e = 0; e < 4; e++) {
                int rowg = m0 + msub + mi * 16 + q * 4 + e;
                float v = a[e] + bb;
                if (EPI == 2) v = gelu_exact(v);
                if (EPI == 0) {
                    ((float*)Cout)[(size_t)rowg * ldc + col] = v;
                } else if (EPI == 1 || EPI == 2) {
                    ((ushort_t*)Cout)[(size_t)rowg * ldc + col] = f2bf(v);
                } else if (EPI == 3) {
                    int b = rowg >> p1, t = rowg & ((1 << p1) - 1);
                    ((ushort_t*)Cout)[(((size_t)(b * 16 + (col >> 6))) * 1792 + p0 + t) * 64 + (col & 63)] = f2bf(v);
                } else if (EPI == 5) {
                    int b = rowg >> p1, t = rowg & ((1 << p1) - 1);
                    ((ushort_t*)Cout)[(((size_t)(b * 16 + (col >> 6))) * 64 + (col & 63)) * 1792 + p0 + t] = f2bf(v);
                } else {  // EPI == 4
                    int b = rowg >> 9, t = rowg & 511;
                    ((ushort_t*)Cout)[((((size_t)(b * 16 + (col >> 6))) * 4 + p0) * 512 + t) * 64 + (col & 63)] = f2bf(v);
                }
            }
        }
    }
}

__global__ void __launch_bounds__(256) qrope_ip_kernel(
    ushort_t* __restrict__ qbuf, const void* __restrict__ qnw,
    const int* __restrict__ dflag) {
    int isf32 = *dflag;
    int w = threadIdx.x >> 6, ln = threadIdx.x & 63;
    int flat = blockIdx.x * 4 + w;
    int t = flat & 511, s = (flat >> 9) & 3;
    ushort_t* p = qbuf + (size_t)flat * 64;
    float x = bf2f(p[ln]);
    float ssum = x * x;
    #pragma unroll
    for (int off = 1; off < 64; off <<= 1) ssum += __shfl_xor(ssum, off, 64);
    float y = x * rsqrtf(ssum * (1.f / 64.f) + 1e-6f) * ld1(qnw, ln, isf32);
    if (s == 0) {
        float ang = (float)t * expf(-(float)(ln & 31) * (9.210340371976184f / 32.f));
        float cs, sn;
        sincosf(ang, &sn, &cs);
        float other = __shfl_xor(y, 32, 64);
        y = y * cs + ((ln < 32) ? -other : other) * sn;
    }
    p[ln] = f2bf(y);
}

__global__ void __launch_bounds__(256) krope_ip_kernel(
    ushort_t* __restrict__ kbuf, const void* __restrict__ knw,
    const int* __restrict__ dflag) {
    int isf32 = *dflag;
    int w = threadIdx.x >> 6, ln = threadIdx.x & 63;
    int flat = blockIdx.x * 4 + w;
    int j = flat % 1792;
    int t = j & 511;
    ushort_t* p = kbuf + (size_t)flat * 64;
    float x = bf2f(p[ln]);
    float ssum = x * x;
    #pragma unroll
    for (int off = 1; off < 64; off <<= 1) ssum += __shfl_xor(ssum, off, 64);
    float y = x * rsqrtf(ssum * (1.f / 64.f) + 1e-6f) * ld1(knw, ln, isf32);
    float ang = (float)t * expf(-(float)(ln & 31) * (9.210340371976184f / 32.f));
    float cs, sn;
    sincosf(ang, &sn, &cs);
    float other = __shfl_xor(y, 32, 64);
    y = y * cs + ((ln < 32) ? -other : other) * sn;
    p[ln] = f2bf(y);
}

// ---------------------------------------------------------------------------
// MFMA flash attention, 64-key double-buffered tiles: ONE barrier per 64 keys
// (was 4), shfl chains per key halved. grid (8, 64), block 256 = 4 waves.
// ---------------------------------------------------------------------------
__global__ void __launch_bounds__(256) attn_mfma_kernel(
    const ushort_t* __restrict__ qbuf, const ushort_t* __restrict__ kbuf,
    const ushort_t* __restrict__ vbufT, const float* __restrict__ consts,
    ushort_t* __restrict__ attn_out) {
    __shared__ ushort_t ks[2][64][72];
    __shared__ ushort_t vsT[2][64][72];
    __shared__ ushort_t ps[4][16][72];
    int bh = blockIdx.y;
    int b = bh >> 4, h = bh & 15;
    int tid = threadIdx.x, w = tid >> 6, ln = tid & 63;
    int r0 = blockIdx.x * 64 + w * 16;
    int m = ln & 15, quad = ln >> 4;

    const ushort_t* qb = qbuf + (size_t)bh * 4 * 512 * 64;
    bf16x8 qf00 = *(const bf16x8*)(qb + ((size_t)(0 * 512 + r0 + m)) * 64 + quad * 8);
    bf16x8 qf01 = *(const bf16x8*)(qb + ((size_t)(0 * 512 + r0 + m)) * 64 + 32 + quad * 8);
    bf16x8 qf10 = *(const bf16x8*)(qb + ((size_t)(1 * 512 + r0 + m)) * 64 + quad * 8);
    bf16x8 qf11 = *(const bf16x8*)(qb + ((size_t)(1 * 512 + r0 + m)) * 64 + 32 + quad * 8);
    bf16x8 qf20 = *(const bf16x8*)(qb + ((size_t)(2 * 512 + r0 + m)) * 64 + quad * 8);
    bf16x8 qf21 = *(const bf16x8*)(qb + ((size_t)(2 * 512 + r0 + m)) * 64 + 32 + quad * 8);
    bf16x8 qf30 = *(const bf16x8*)(qb + ((size_t)(3 * 512 + r0 + m)) * 64 + quad * 8);
    bf16x8 qf31 = *(const bf16x8*)(qb + ((size_t)(3 * 512 + r0 + m)) * 64 + 32 + quad * 8);

    float m_i[4], l_i[4];
    f32x4 acc[4];
    #pragma unroll
    for (int e = 0; e < 4; e++) { m_i[e] = -1e30f; l_i[e] = 0.f; }
    #pragma unroll
    for (int d = 0; d < 4; d++) acc[d] = (f32x4){0.f, 0.f, 0.f, 0.f};

    const ushort_t* kb  = kbuf  + (size_t)bh * 1792 * 64;
    const ushort_t* vbT = vbufT + (size_t)bh * 64 * 1792;
    int skey = tid >> 3, sd = (tid & 7) * 8;   // K: keys 0..31 (+32), d slice
                                               // V^T: rows(d) 0..31 (+32), key slice
    uint4 kreg0 = *(const uint4*)(kb + (size_t)skey * 64 + sd);
    uint4 kreg1 = *(const uint4*)(kb + (size_t)(skey + 32) * 64 + sd);
    uint4 vreg0 = *(const uint4*)(vbT + (size_t)skey * 1792 + sd);
    uint4 vreg1 = *(const uint4*)(vbT + (size_t)(skey + 32) * 1792 + sd);
    *(uint4*)&ks[0][skey][sd]       = kreg0;
    *(uint4*)&ks[0][skey + 32][sd]  = kreg1;
    *(uint4*)&vsT[0][skey][sd]      = vreg0;
    *(uint4*)&vsT[0][skey + 32][sd] = vreg1;
    __syncthreads();
    int tcnt = 0, p = 0;

    #pragma unroll
    for (int s = 0; s < 4; s++) {
        const float a_s = consts[s];
        const float b_s = consts[4 + s];
        const bf16x8 qA0 = (s == 0) ? qf00 : (s == 1) ? qf10 : (s == 2) ? qf20 : qf30;
        const bf16x8 qA1 = (s == 0) ? qf01 : (s == 1) ? qf11 : (s == 2) ? qf21 : qf31;
        const int NT = (s == 3) ? 4 : 8;
        for (int ti = 0; ti < NT; ti++) {
            if (tcnt < 27) {               // prefetch next 64-key tile into regs
                int nx = (tcnt + 1) * 64;
                kreg0 = *(const uint4*)(kb + (size_t)(nx + skey) * 64 + sd);
                kreg1 = *(const uint4*)(kb + (size_t)(nx + skey + 32) * 64 + sd);
                vreg0 = *(const uint4*)(vbT + (size_t)skey * 1792 + nx + sd);
                vreg1 = *(const uint4*)(vbT + (size_t)(skey + 32) * 1792 + nx + sd);
            }
            // QK^T: S[16q x 64key] as four C-frags
            f32x4 zero = {0.f, 0.f, 0.f, 0.f};
            bf16x8 k0a = *(const bf16x8*)&ks[p][m][quad * 8];
            bf16x8 k0b = *(const bf16x8*)&ks[p][m][32 + quad * 8];
            bf16x8 k1a = *(const bf16x8*)&ks[p][16 + m][quad * 8];
            bf16x8 k1b = *(const bf16x8*)&ks[p][16 + m][32 + quad * 8];
            bf16x8 k2a = *(const bf16x8*)&ks[p][32 + m][quad * 8];
            bf16x8 k2b = *(const bf16x8*)&ks[p][32 + m][32 + quad * 8];
            bf16x8 k3a = *(const bf16x8*)&ks[p][48 + m][quad * 8];
            bf16x8 k3b = *(const bf16x8*)&ks[p][48 + m][32 + quad * 8];
            f32x4 sc0 = __builtin_amdgcn_mfma_f32_16x16x32_bf16(qA0, k0a, zero, 0, 0, 0);
            sc0 = __builtin_amdgcn_mfma_f32_16x16x32_bf16(qA1, k0b, sc0, 0, 0, 0);
            f32x4 sc1 = __builtin_amdgcn_mfma_f32_16x16x32_bf16(qA0, k1a, zero, 0, 0, 0);
            sc1 = __builtin_amdgcn_mfma_f32_16x16x32_bf16(qA1, k1b, sc1, 0, 0, 0);
            f32x4 sc2 = __builtin_amdgcn_mfma_f32_16x16x32_bf16(qA0, k2a, zero, 0, 0, 0);
            sc2 = __builtin_amdgcn_mfma_f32_16x16x32_bf16(qA1, k2b, sc2, 0, 0, 0);
            f32x4 sc3 = __builtin_amdgcn_mfma_f32_16x16x32_bf16(qA0, k3a, zero, 0, 0, 0);
            sc3 = __builtin_amdgcn_mfma_f32_16x16x32_bf16(qA1, k3b, sc3, 0, 0, 0);
            // online softmax per row (row = quad*4+e), reduce over 16 m-lanes
            #pragma unroll
            for (int e = 0; e < 4; e++) {
                float s0 = sc0[e] * a_s + b_s;
                float s1 = sc1[e] * a_s + b_s;
                float s2 = sc2[e] * a_s + b_s;
                float s3 = sc3[e] * a_s + b_s;
                float mxe = fmaxf(fmaxf(s0, s1), fmaxf(s2, s3));
                #pragma unroll
                for (int off = 1; off < 16; off <<= 1) mxe = fmaxf(mxe, __shfl_xor(mxe, off, 64));
                float mnew = fmaxf(m_i[e], mxe);
                float p0 = __expf(s0 - mnew), p1 = __expf(s1 - mnew);
                float p2 = __expf(s2 - mnew), p3 = __expf(s3 - mnew);
                float rsum = (p0 + p1) + (p2 + p3);
                #pragma unroll
                for (int off = 1; off < 16; off <<= 1) rsum += __shfl_xor(rsum, off, 64);
                float alpha = __expf(m_i[e] - mnew);
                m_i[e] = mnew;
                l_i[e] = l_i[e] * alpha + rsum;
                acc[0][e] *= alpha; acc[1][e] *= alpha;
                acc[2][e] *= alpha; acc[3][e] *= alpha;
                int row = quad * 4 + e;
                ps[w][row][m]      = f2bf(p0);
                ps[w][row][m + 16] = f2bf(p1);
                ps[w][row][m + 32] = f2bf(p2);
                ps[w][row][m + 48] = f2bf(p3);
            }
            // PV: per-wave ps, intra-wave lgkmcnt ordering suffices
            bf16x8 pA0 = *(const bf16x8*)&ps[w][m][quad * 8];
            bf16x8 pA1 = *(const bf16x8*)&ps[w][m][32 + quad * 8];
            #pragma unroll
            for (int dsub = 0; dsub < 4; dsub++) {
                bf16x8 vB0 = *(const bf16x8*)&vsT[p][dsub * 16 + m][quad * 8];
                bf16x8 vB1 = *(const bf16x8*)&vsT[p][dsub * 16 + m][32 + quad * 8];
                acc[dsub] = __builtin_amdgcn_mfma_f32_16x16x32_bf16(pA0, vB0, acc[dsub], 0, 0, 0);
                acc[dsub] = __builtin_amdgcn_mfma_f32_16x16x32_bf16(pA1, vB1, acc[dsub], 0, 0, 0);
            }
            // stage prefetched tile into the other buffer; single barrier
            if (tcnt < 27) {
                *(uint4*)&ks[1 - p][skey][sd]       = kreg0;
                *(uint4*)&ks[1 - p][skey + 32][sd]  = kreg1;
                *(uint4*)&vsT[1 - p][skey][sd]      = vreg0;
                *(uint4*)&vsT[1 - p][skey + 32][sd] = vreg1;
            }
            __syncthreads();
            p ^= 1;
            tcnt++;
        }
    }
    #pragma unroll
    for (int e = 0; e < 4; e++) {
        int t = r0 + quad * 4 + e;
        float invl = 1.f / l_i[e];
        #pragma unroll
        for (int dsub = 0; dsub < 4; dsub++) {
            int d = dsub * 16 + m;
            attn_out[(((size_t)(b * 512 + t)) * 16 + h) * 64 + d] = f2bf(acc[dsub][e] * invl);
        }
    }
}

__global__ void resgate_kernel(const void* __restrict__ x, const float* __restrict__ proj,
                               const float* __restrict__ mod, float* __restrict__ x1,
                               const int* __restrict__ dflag) {
    int isf32 = *dflag;
    int i = blockIdx.x * 256 + threadIdx.x;
    int b = i >> 19, n = i & 1023;
    x1[i] = ld1(x, i, isf32) + mod[(size_t)b * 6144 + 2048 + n] * proj[i];
}
__global__ void final_kernel(const float* __restrict__ x1, const float* __restrict__ ffn,
                             const float* __restrict__ mod, void* __restrict__ out,
                             const int* __restrict__ dflag) {
    int isf32 = *dflag;
    int i = blockIdx.x * 256 + threadIdx.x;
    int b = i >> 19, n = i & 1023;
    float val = x1[i] + mod[(size_t)b * 6144 + 5120 + n] * ffn[i];
    if (isf32) ((float*)out)[i] = val;
    else       ((ushort_t*)out)[i] = f2bf(val);
}

static constexpr size_t OFF_CONSTS   = 0;
static constexpr size_t OFF_FLAG     = 64;
static constexpr size_t OFF_MOD      = 512;
static constexpr size_t OFF_XNORM    = OFF_MOD    + 98304;
static constexpr size_t OFF_QAH      = OFF_XNORM  + 4194304;
static constexpr size_t OFF_KBUF     = OFF_XNORM  + 8388608;
static constexpr size_t OFF_VBUF     = OFF_KBUF   + 14680064;   // vbufT[bh][d][key]
static constexpr size_t OFF_QBUF     = OFF_VBUF   + 14680064;
static constexpr size_t OFF_ATTNOUT  = OFF_QBUF   + 16777216;
static constexpr size_t OFF_X1       = OFF_XNORM;
static constexpr size_t OFF_ATTNPROJ = OFF_QBUF;
static constexpr size_t OFF_FFNOUT   = OFF_QBUF   + 8388608;
static constexpr size_t OFF_HMID     = OFF_KBUF;
static constexpr size_t OFF_HIN      = OFF_ATTNOUT;
static constexpr size_t OFF_WCACHE   = OFF_ATTNOUT + 4194304;   // bf16 weight cache
static constexpr size_t WS_NEED      = OFF_WCACHE + CV_TOTAL * 2;

extern "C" void kernel_launch(void* const* d_in, const int* in_sizes, int n_in,
                              void* d_out, int out_size, void* d_ws, size_t ws_size,
                              hipStream_t stream) {
    (void)in_sizes; (void)n_in; (void)out_size;
    const void* x        = d_in[0];
    const void* bev      = d_in[1];
    const void* vl       = d_in[2];
    const void* reas     = d_in[3];
    const void* cond     = d_in[4];
    const void* ln_pre_w = d_in[5];
    const void* ln_pre_b = d_in[6];
    const void* adaln_w  = d_in[7];
    const void* adaln_b  = d_in[8];
    const void* q_proj_w = d_in[9];
    const void* q_proj_b = d_in[10];
    const void* qa_w     = d_in[11];
    const void* qa_b     = d_in[12];
    const void* qa_out_w = d_in[13];
    const void* qa_out_b = d_in[14];
    const void* k_w      = d_in[15];
    const void* k_b      = d_in[16];
    const void* v_w      = d_in[17];
    const void* v_b      = d_in[18];
    const void* o_w      = d_in[19];
    const void* o_b      = d_in[20];
    const void* qn_w     = d_in[21];
    const void* kn_w     = d_in[22];
    const void* gating   = d_in[23];
    const void* temps    = d_in[24];
    const void* sbias    = d_in[25];
    const void* ffn_ln_w = d_in[26];
    const void* ffn_ln_b = d_in[27];
    const void* ffn_w1   = d_in[28];
    const void* ffn_b1   = d_in[29];
    const void* ffn_w2   = d_in[30];
    const void* ffn_b2   = d_in[31];

    char* ws = (char*)d_ws;
    float*    consts   = (float*)(ws + OFF_CONSTS);
    int*      dflag    = (int*)(ws + OFF_FLAG);
    float*    mod      = (float*)(ws + OFF_MOD);
    ushort_t* xnorm    = (ushort_t*)(ws + OFF_XNORM);
    ushort_t* qah      = (ushort_t*)(ws + OFF_QAH);
    ushort_t* kbuf     = (ushort_t*)(ws + OFF_KBUF);
    ushort_t* vbufT    = (ushort_t*)(ws + OFF_VBUF);
    ushort_t* qbuf     = (ushort_t*)(ws + OFF_QBUF);
    ushort_t* attnout  = (ushort_t*)(ws + OFF_ATTNOUT);
    float*    x1       = (float*)(ws + OFF_X1);
    float*    attnproj = (float*)(ws + OFF_ATTNPROJ);
    float*    ffnout   = (float*)(ws + OFF_FFNOUT);
    ushort_t* hmid     = (ushort_t*)(ws + OFF_HMID);
    ushort_t* hin      = (ushort_t*)(ws + OFF_HIN);
    ushort_t* wc       = (ushort_t*)(ws + OFF_WCACHE);

    const bool use_cache = (ws_size >= WS_NEED);
    const int  wm = use_cache ? 2 : 0;
    const void* W_adaln = use_cache ? (const void*)(wc + CV_ADALN) : adaln_w;
    const void* W_qproj = use_cache ? (const void*)(wc + CV_QPROJ) : q_proj_w;
    const void* W_qa    = use_cache ? (const void*)(wc + CV_QA)    : qa_w;
    const void* W_qaout = use_cache ? (const void*)(wc + CV_QAOUT) : qa_out_w;
    const void* W_k     = use_cache ? (const void*)(wc + CV_KW)    : k_w;
    const void* W_v     = use_cache ? (const void*)(wc + CV_VW)    : v_w;
    const void* W_o     = use_cache ? (const void*)(wc + CV_OW)    : o_w;
    const void* W_ffn1  = use_cache ? (const void*)(wc + CV_FFN1)  : ffn_w1;
    const void* W_ffn2  = use_cache ? (const void*)(wc + CV_FFN2)  : ffn_w2;

    detect_kernel<<<1, 64, 0, stream>>>((const unsigned int*)x, dflag);
    if (use_cache)
        convert_weights_kernel<<<12800, 256, 0, stream>>>(
            adaln_w, q_proj_w, qa_w, qa_out_w, k_w, v_w, o_w, ffn_w1, ffn_w2, wc, dflag);
    prep_consts_kernel<<<1, 64, 0, stream>>>(temps, sbias, gating, consts, dflag);
    adaln_kernel<<<dim3(24, 4), 256, 0, stream>>>(cond, W_adaln, adaln_b, mod, wm, dflag);
    ln_mod_kernel<0><<<2048, 256, 0, stream>>>(x, mod, ln_pre_w, ln_pre_b, 0, 1024, xnorm, dflag);
    // grids are (M/64, N/64) now — x = M fast-moving so concurrent blocks share W rows
    gemm_bt_kernel<4><<<dim3(32, 16), 256, 0, stream>>>(xnorm, 1024, W_qproj, 0, q_proj_b, qbuf, 0, 1024, 0, 9, 0, wm, dflag);
    {
        const void* srcs[4] = {xnorm, bev, vl, reas};
        const int koffs[4] = {0, 512, 1024, 1536};
        const int p1s[4]   = {9, 9, 9, 8};
        for (int i = 0; i < 4; i++) {
            int aext = (i == 0) ? 0 : 1;
            int gx = (i == 3) ? 16 : 32;   // M/64
            gemm_bt_kernel<3><<<dim3(gx, 16), 256, 0, stream>>>(
                srcs[i], 1024, W_k, i * 1024, k_b, kbuf, 0, 1024, koffs[i], p1s[i], aext, wm, dflag);
            gemm_bt_kernel<5><<<dim3(gx, 16), 256, 0, stream>>>(
                srcs[i], 1024, W_v, i * 1024, v_b, vbufT, 0, 1024, koffs[i], p1s[i], aext, wm, dflag);
        }
    }
    gemm_bt_kernel<1><<<dim3(32, 12), 256, 0, stream>>>(xnorm, 1024, W_qa, 0, qa_b, qah, 768, 1024, 0, 0, 0, wm, dflag);
    for (int i = 0; i < 3; i++)
        gemm_bt_kernel<4><<<dim3(32, 16), 256, 0, stream>>>(qah + i * 256, 768, W_qaout, 0, qa_out_b,
                                                            qbuf, 0, 256, 1 + i, 9, 0, wm, dflag);
    qrope_ip_kernel<<<32768, 256, 0, stream>>>(qbuf, qn_w, dflag);
    krope_ip_kernel<<<28672, 256, 0, stream>>>(kbuf, kn_w, dflag);
    attn_mfma_kernel<<<dim3(8, 64), 256, 0, stream>>>(qbuf, kbuf, vbufT, consts, attnout);
    gemm_bt_kernel<0><<<dim3(32, 16), 256, 0, stream>>>(attnout, 1024, W_o, 0, o_b, attnproj, 1024, 1024, 0, 0, 0, wm, dflag);
    resgate_kernel<<<8192, 256, 0, stream>>>(x, attnproj, mod, x1, dflag);
    ln_mod_kernel<1><<<2048, 256, 0, stream>>>(x1, mod, ffn_ln_w, ffn_ln_b, 3072, 4096, hin, dflag);
    gemm_bt_kernel<2><<<dim3(32, 64), 256, 0, stream>>>(hin, 1024, W_ffn1, 0, ffn_b1, hmid, 4096, 1024, 0, 0, 0, wm, dflag);
    gemm_bt_kernel<0><<<dim3(32, 16), 256, 0, stream>>>(hmid, 4096, W_ffn2, 0, ffn_b2, ffnout, 1024, 4096, 0, 0, 0, wm, dflag);
    final_kernel<<<8192, 256, 0, stream>>>(x1, ffnout, mod, d_out, dflag);
}